// Round 3
// baseline (1378.169 us; speedup 1.0000x reference)
//
#include <hip/hip_runtime.h>
#include <hip/hip_bf16.h>

#define NPTS 200000
#define CIN 64
#define COUT 64
#define KVOL 27
#define NPAIRS 100000
#define NPAIRS_TOT (KVOL * NPAIRS)                       // 2,700,000
#define NTILES (NPTS / 16)                               // 12,500 output tiles of 16 rows
#define NKEYS (NTILES * KVOL)                            // 337,500 (tile,k) buckets
#define SCAN_ITEMS 2048
#define NSCANB ((NKEYS + SCAN_ITEMS - 1) / SCAN_ITEMS)   // 165
#define BN_EPS 1e-5f

static_assert(NPTS % 16 == 0, "tiles");
static_assert(NTILES % 4 == 0, "4 waves/block");
static_assert(NSCANB <= 256, "single-block top scan");

typedef __attribute__((ext_vector_type(8))) short short8;   // 8 bf16 (4 VGPRs)
typedef __attribute__((ext_vector_type(4))) float f32x4;

__device__ inline ushort f2bf(float x) {
    union { __hip_bfloat16 h; ushort u; } cv;
    cv.h = __float2bfloat16(x);   // RNE
    return cv.u;
}

// ---------- preprocessing: counting sort of contributions by (out_tile, k) ----------
// Global f32 scatter atomics were the R0 service-rate ceiling (WRITE_SIZE 675MB =
// 13.2x ideal). Sorting lets the conv kernel accumulate in wave-private LDS and write
// each output row exactly once.
// R1/R2 FAILURE ROOT CAUSE: workspace overlap — cursor [5MiB, 6.59MiB) ran over
// wt at 6MiB, so 2.7M cursor atomics rewrote the weights with int bits (incl.
// 0xFF80 = bf16 -inf). Fixed by moving wt to 7MiB. (Slot arithmetic now in bytes.)

// W[k][cin][cout] fp32  ->  Wt[k][cout][cin] bf16, so B-fragments load as dwordx4.
__global__ __launch_bounds__(256) void wprep_kernel(const float* __restrict__ wk,
                                                    ushort* __restrict__ wt) {
    const int i = blockIdx.x * 256 + threadIdx.x;     // over KVOL*64*64 = 110,592
    if (i >= KVOL * CIN * COUT) return;
    const int k = i >> 12, r = i & 4095, co = r >> 6, ci = r & 63;
    wt[i] = f2bf(wk[(k << 12) | (ci << 6) | co]);
}

__global__ __launch_bounds__(256) void hist_kernel(const int* __restrict__ omap,
                                                   int* __restrict__ cnt) {
    for (int i = blockIdx.x * 256 + threadIdx.x; i < NPAIRS_TOT; i += gridDim.x * 256) {
        const int k = i / NPAIRS;                     // magic-mul div
        atomicAdd(&cnt[(omap[i] >> 4) * KVOL + k], 1);
    }
}

// 2-level exclusive scan over NKEYS counters (165 blocks x 2048 items).
__global__ __launch_bounds__(256) void scan1_kernel(const int* __restrict__ cnt,
                                                    int* __restrict__ offs,
                                                    int* __restrict__ bsum) {
    __shared__ int s[256];
    const int t = threadIdx.x;
    const int base = blockIdx.x * SCAN_ITEMS + t * 8;
    int v[8]; int sum = 0;
    #pragma unroll
    for (int i = 0; i < 8; ++i) {
        const int idx = base + i;
        v[i] = (idx < NKEYS) ? cnt[idx] : 0;
        sum += v[i];
    }
    s[t] = sum;
    __syncthreads();
    for (int off = 1; off < 256; off <<= 1) {         // Hillis-Steele inclusive
        const int x = (t >= off) ? s[t - off] : 0;
        __syncthreads();
        s[t] += x;
        __syncthreads();
    }
    if (t == 255) bsum[blockIdx.x] = s[255];
    int run = s[t] - sum;                             // exclusive prefix of this thread
    #pragma unroll
    for (int i = 0; i < 8; ++i) {
        const int idx = base + i;
        if (idx < NKEYS) offs[idx] = run;
        run += v[i];
    }
}

__global__ __launch_bounds__(256) void scan2_kernel(int* __restrict__ bsum) {
    __shared__ int s[256];
    const int t = threadIdx.x;
    const int v = (t < NSCANB) ? bsum[t] : 0;
    s[t] = v;
    __syncthreads();
    for (int off = 1; off < 256; off <<= 1) {
        const int x = (t >= off) ? s[t - off] : 0;
        __syncthreads();
        s[t] += x;
        __syncthreads();
    }
    if (t < NSCANB) bsum[t] = s[t] - v;               // exclusive block offsets
}

__global__ __launch_bounds__(256) void scan3_kernel(int* __restrict__ offs,
                                                    int* __restrict__ cursor,
                                                    const int* __restrict__ bsum) {
    const int base = blockIdx.x * SCAN_ITEMS + threadIdx.x * 8;
    const int add = bsum[blockIdx.x];
    #pragma unroll
    for (int i = 0; i < 8; ++i) {
        const int idx = base + i;
        if (idx < NKEYS) {
            const int v = offs[idx] + add;
            offs[idx] = v;
            cursor[idx] = v;                          // fill cursors start at bucket base
        }
    }
}

// payload = in_row (18b) | local_out_row (4b) << 18
__global__ __launch_bounds__(256) void fill_kernel(const int* __restrict__ imap,
                                                   const int* __restrict__ omap,
                                                   int* __restrict__ cursor,
                                                   unsigned* __restrict__ payload) {
    for (int i = blockIdx.x * 256 + threadIdx.x; i < NPAIRS_TOT; i += gridDim.x * 256) {
        const int k = i / NPAIRS;
        const int o = omap[i];
        const int key = (o >> 4) * KVOL + k;
        const int pos = atomicAdd(&cursor[key], 1);
        payload[pos] = (unsigned)imap[i] | ((unsigned)(o & 15) << 18);
    }
}

// ---------- output-stationary conv: gather -> MFMA -> LDS accumulate -> BN+ReLU ----------
// Wave owns one 16-row output tile (LDS [16][65] f32, +1 pad breaks the row-stride-64
// 4-way bank alias). Per k: B-frags from Wt (L2-hot), chunks of <=16 bucket entries:
//   A[m=lane&15][kin=q*8+e] from feats[payload&0x3FFFF]  (verified layout)
//   D: pair=q*4+r, cout=nt*16+(lane&15)                   (verified layout)
// Scatter via plain atomicAdd on LDS (native ds fp32 atomic; unsafeAtomicAdd is
// global-only). Epilogue: BN fold + ReLU + single coalesced global write ->
// no accum buffer, no memset, no second pass.
__global__ __launch_bounds__(256) void conv_gather_kernel(
    const float* __restrict__ feats,
    const ushort* __restrict__ wt,
    const unsigned* __restrict__ payload,
    const int* __restrict__ offs,
    const float* __restrict__ gamma,
    const float* __restrict__ beta,
    const float* __restrict__ rmean,
    const float* __restrict__ rvar,
    float* __restrict__ out)
{
    __shared__ float tile[4][16 * 65];
    const int lane = threadIdx.x & 63;
    const int wave = threadIdx.x >> 6;
    const int m = lane & 15;
    const int q = lane >> 4;
    const int t = blockIdx.x * 4 + wave;

    for (int i = lane; i < 16 * 65; i += 64) tile[wave][i] = 0.f;

    const float sc = gamma[lane] * rsqrtf(rvar[lane] + BN_EPS);
    const float bi = beta[lane] - rmean[lane] * sc;

    for (int k = 0; k < KVOL; ++k) {
        short8 bfrag[2][4];
        #pragma unroll
        for (int h = 0; h < 2; ++h)
            #pragma unroll
            for (int nt = 0; nt < 4; ++nt)
                bfrag[h][nt] = *(const short8*)(wt + ((k * 64 + nt * 16 + m) * 64 + h * 32 + q * 8));

        const int key = t * KVOL + k;
        const int e0 = offs[key];
        const int e1 = (key + 1 < NKEYS) ? offs[key + 1] : NPAIRS_TOT;

        for (int base = e0; base < e1; base += 16) {
            const int ei = base + m;
            const bool av = (ei < e1);
            unsigned pl = 0u;
            f32x4 f00 = (f32x4){0.f, 0.f, 0.f, 0.f}, f01 = f00, f10 = f00, f11 = f00;
            if (av) {
                pl = payload[ei];
                const float* fr = feats + (size_t)(pl & 0x3FFFFu) * CIN + q * 8;
                f00 = *(const f32x4*)(fr);
                f01 = *(const f32x4*)(fr + 4);
                f10 = *(const f32x4*)(fr + 32);
                f11 = *(const f32x4*)(fr + 36);
            }
            short8 a0, a1;
            #pragma unroll
            for (int e = 0; e < 4; ++e) {
                a0[e]     = (short)f2bf(f00[e]);
                a0[e + 4] = (short)f2bf(f01[e]);
                a1[e]     = (short)f2bf(f10[e]);
                a1[e + 4] = (short)f2bf(f11[e]);
            }

            // local rows for this lane's 4 output pairs (uniform flow for the shfl;
            // source lane p<16 loaded payload[base+p] iff base+p<e1, exactly when used)
            unsigned plr[4];
            #pragma unroll
            for (int r = 0; r < 4; ++r) plr[r] = (unsigned)__shfl((int)pl, q * 4 + r);

            f32x4 acc[4];
            #pragma unroll
            for (int nt = 0; nt < 4; ++nt) acc[nt] = (f32x4){0.f, 0.f, 0.f, 0.f};
            #pragma unroll
            for (int nt = 0; nt < 4; ++nt) {
                acc[nt] = __builtin_amdgcn_mfma_f32_16x16x32_bf16(a0, bfrag[0][nt], acc[nt], 0, 0, 0);
                acc[nt] = __builtin_amdgcn_mfma_f32_16x16x32_bf16(a1, bfrag[1][nt], acc[nt], 0, 0, 0);
            }

            #pragma unroll
            for (int r = 0; r < 4; ++r) {
                if (base + q * 4 + r < e1) {
                    const int l = (int)((plr[r] >> 18) & 15u);
                    #pragma unroll
                    for (int nt = 0; nt < 4; ++nt)
                        atomicAdd(&tile[wave][l * 65 + nt * 16 + m], acc[nt][r]);
                }
            }
        }
    }

    __syncthreads();   // drains LDS ops before the re-read
    #pragma unroll
    for (int r = 0; r < 16; ++r) {
        const float v = tile[wave][r * 65 + lane];
        out[((size_t)t * 16 + r) * COUT + lane] = fmaxf(v * sc + bi, 0.f);
    }
}

extern "C" void kernel_launch(void* const* d_in, const int* in_sizes, int n_in,
                              void* d_out, int out_size, void* d_ws, size_t ws_size,
                              hipStream_t stream) {
    const float* feats = (const float*)d_in[0];
    const float* wk    = (const float*)d_in[1];
    const float* gamma = (const float*)d_in[2];
    const float* beta  = (const float*)d_in[3];
    const float* rmean = (const float*)d_in[4];
    const float* rvar  = (const float*)d_in[5];
    const int* imap    = (const int*)d_in[6];
    const int* omap    = (const int*)d_in[7];
    float* out         = (float*)d_out;

    // workspace carve — byte-verified disjoint:
    //   cnt     [0        , 1,350,000)
    //   offs    [2,097,152, 3,447,152)
    //   bsum    [4,194,304, 4,194,964)
    //   cursor  [5,242,880, 6,592,880)   <- 1.35MB, spills past 6MiB
    //   wt      [7,340,032, 7,561,216)   <- moved from 6MiB (R1/R2 overlap bug)
    //   payload [8,388,608, 19,188,608)
    char* ws = (char*)d_ws;
    int* cnt          = (int*)(ws);
    int* offs         = (int*)(ws + (2u << 20));
    int* bsum         = (int*)(ws + (4u << 20));
    int* cursor       = (int*)(ws + (5u << 20));
    ushort* wt        = (ushort*)(ws + (7u << 20));
    unsigned* payload = (unsigned*)(ws + (8u << 20));

    hipMemsetAsync(cnt, 0, NKEYS * sizeof(int), stream);
    wprep_kernel<<<(KVOL * CIN * COUT + 255) / 256, 256, 0, stream>>>(wk, wt);
    hist_kernel<<<2048, 256, 0, stream>>>(omap, cnt);
    scan1_kernel<<<NSCANB, 256, 0, stream>>>(cnt, offs, bsum);
    scan2_kernel<<<1, 256, 0, stream>>>(bsum);
    scan3_kernel<<<NSCANB, 256, 0, stream>>>(offs, cursor, bsum);
    fill_kernel<<<2048, 256, 0, stream>>>(imap, omap, cursor, payload);
    conv_gather_kernel<<<NTILES / 4, 256, 0, stream>>>(
        feats, wt, payload, offs, gamma, beta, rmean, rvar, out);
}